// Round 4
// baseline (141.877 us; speedup 1.0000x reference)
//
#include <hip/hip_runtime.h>
#include <hip/hip_fp16.h>

#define DD 64
#define NPB 64          // nodes per block (node kernel)
#define LS 68           // padded LDS row stride (floats)

typedef float vf4 __attribute__((ext_vector_type(4)));

// Node-level transform, GEMM-tiled:
//   A = (K_h + P_e) @ W1 + b1   (stored fp16)
//   B = Q_h @ W1                (stored fp16)
__global__ __launch_bounds__(256) void node_transform_kernel(
    const float* __restrict__ K_h, const float* __restrict__ Q_h,
    const float* __restrict__ P_e, const float* __restrict__ W1,
    const float* __restrict__ b1, __half* __restrict__ A,
    __half* __restrict__ Bm, int n_nodes)
{
    __shared__ float kpT[DD][LS];  // [k][node_local]  (K+P, transposed)
    __shared__ float qT [DD][LS];  // [k][node_local]  (Q, transposed)
    __shared__ float ws [DD][DD];  // [k][c] — same layout as global W1

    const int tid   = threadIdx.x;
    const int nbase = blockIdx.x * NPB;

    // ---- Stage W1 straight copy (16 KB): coalesced float4 ----
    {
        const float4* w4 = (const float4*)W1;
        float4* s4 = (float4*)&ws[0][0];
#pragma unroll
        for (int j = 0; j < 4; ++j) {
            int idx = tid + j * 256;   // 1024 float4 total
            s4[idx] = w4[idx];
        }
    }

    // ---- Stage X transposed ----
#pragma unroll
    for (int j = 0; j < 4; ++j) {
        int chunk = tid + j * 256;        // float4 index over [64 nodes][16]
        int r  = chunk >> 4;              // node_local 0..63
        int k0 = (chunk & 15) << 2;       // 0,4,...,60
        int node = nbase + r;
        float4 kv = make_float4(0.f, 0.f, 0.f, 0.f);
        float4 pv = kv, qv = kv;
        if (node < n_nodes) {
            kv = *(const float4*)(K_h + (size_t)node * DD + k0);
            pv = *(const float4*)(P_e + (size_t)node * DD + k0);
            qv = *(const float4*)(Q_h + (size_t)node * DD + k0);
        }
        kpT[k0 + 0][r] = kv.x + pv.x;
        kpT[k0 + 1][r] = kv.y + pv.y;
        kpT[k0 + 2][r] = kv.z + pv.z;
        kpT[k0 + 3][r] = kv.w + pv.w;
        qT [k0 + 0][r] = qv.x;
        qT [k0 + 1][r] = qv.y;
        qT [k0 + 2][r] = qv.z;
        qT [k0 + 3][r] = qv.w;
    }
    __syncthreads();

    // ---- Main loop: 4x4 micro-tile, dual accumulators (A and B) ----
    const int tx = tid & 15;
    const int ty = tid >> 4;
    const int c0 = tx * 4;
    const int r0 = ty * 4;

    float4 bv = *(const float4*)(b1 + c0);   // fold b1 into A accumulator
    float accA[4][4], accB[4][4];
#pragma unroll
    for (int r = 0; r < 4; ++r) {
        accA[r][0] = bv.x; accA[r][1] = bv.y; accA[r][2] = bv.z; accA[r][3] = bv.w;
        accB[r][0] = 0.f;  accB[r][1] = 0.f;  accB[r][2] = 0.f;  accB[r][3] = 0.f;
    }

#pragma unroll 8
    for (int k = 0; k < DD; ++k) {
        float4 a4 = *(const float4*)&kpT[k][r0];
        float4 q4 = *(const float4*)&qT [k][r0];
        float4 w4 = *(const float4*)&ws [k][c0];
        const float av[4] = {a4.x, a4.y, a4.z, a4.w};
        const float qv[4] = {q4.x, q4.y, q4.z, q4.w};
        const float wv[4] = {w4.x, w4.y, w4.z, w4.w};
#pragma unroll
        for (int r = 0; r < 4; ++r) {
#pragma unroll
            for (int c = 0; c < 4; ++c) {
                accA[r][c] = fmaf(av[r], wv[c], accA[r][c]);
                accB[r][c] = fmaf(qv[r], wv[c], accB[r][c]);
            }
        }
    }

    // ---- Epilogue: convert to fp16, 8 B stores ----
#pragma unroll
    for (int r = 0; r < 4; ++r) {
        int node = nbase + r0 + r;
        if (node >= n_nodes) continue;
        union { __half2 h[2]; float2 f; } ua, ub;
        ua.h[0] = __float22half2_rn(make_float2(accA[r][0], accA[r][1]));
        ua.h[1] = __float22half2_rn(make_float2(accA[r][2], accA[r][3]));
        ub.h[0] = __float22half2_rn(make_float2(accB[r][0], accB[r][1]));
        ub.h[1] = __float22half2_rn(make_float2(accB[r][2], accB[r][3]));
        *(float2*)(A  + (size_t)node * DD + c0) = ua.f;
        *(float2*)(Bm + (size_t)node * DD + c0) = ub.f;
    }
}

// Edge-level: score[e] = relu(A[src[e]] - B[dst[e]]) . W2 + b2
// 8 lanes cooperate per edge, 2 edges per lane-group:
//  - 4 row loads (nontemporal: each gathered 128-B line is consumed by ONE
//    instruction, L1 retention is pure pollution) issued before consumption
//    -> 32 outstanding line requests per wave for latency hiding.
//  - lane 0 writes both adjacent scores as one float2.
__global__ __launch_bounds__(256) void edge_score_kernel(
    const __half* __restrict__ A, const __half* __restrict__ Bm,
    const int* __restrict__ src, const int* __restrict__ dst,
    const float* __restrict__ W2, const float* __restrict__ b2,
    float* __restrict__ out, int n_edges)
{
    const int tid = threadIdx.x;
    const int g   = tid >> 3;                 // lane-group 0..31
    const int c   = tid & 7;                  // 16B chunk within row
    const int e0  = (blockIdx.x << 6) + (g << 1);   // 64 edges per block
    const int e1  = e0 + 1;
    if (e0 >= n_edges) return;

    const int s0 = src[e0], d0 = dst[e0];
    const bool has1 = (e1 < n_edges);
    const int s1 = has1 ? src[e1] : s0;
    const int d1 = has1 ? dst[e1] : d0;

    // Issue all 4 row loads back-to-back.
    vf4 a0 = __builtin_nontemporal_load((const vf4*)(A  + (size_t)s0 * DD + c * 8));
    vf4 b0 = __builtin_nontemporal_load((const vf4*)(Bm + (size_t)d0 * DD + c * 8));
    vf4 a1 = __builtin_nontemporal_load((const vf4*)(A  + (size_t)s1 * DD + c * 8));
    vf4 b1v = __builtin_nontemporal_load((const vf4*)(Bm + (size_t)d1 * DD + c * 8));

    float4 w0 = *(const float4*)(W2 + c * 8);       // uniform -> s_load
    float4 w1 = *(const float4*)(W2 + c * 8 + 4);
    const float wv[8] = {w0.x, w0.y, w0.z, w0.w, w1.x, w1.y, w1.z, w1.w};

    union { vf4 v; __half2 h[4]; } ua0, ub0, ua1, ub1;
    ua0.v = a0; ub0.v = b0; ua1.v = a1; ub1.v = b1v;

    float acc0 = 0.f, acc1 = 0.f;
#pragma unroll
    for (int j = 0; j < 4; ++j) {
        float2 x0 = __half22float2(ua0.h[j]);
        float2 y0 = __half22float2(ub0.h[j]);
        float2 x1 = __half22float2(ua1.h[j]);
        float2 y1 = __half22float2(ub1.h[j]);
        acc0 = fmaf(fmaxf(x0.x - y0.x, 0.f), wv[2 * j + 0], acc0);
        acc0 = fmaf(fmaxf(x0.y - y0.y, 0.f), wv[2 * j + 1], acc0);
        acc1 = fmaf(fmaxf(x1.x - y1.x, 0.f), wv[2 * j + 0], acc1);
        acc1 = fmaf(fmaxf(x1.y - y1.y, 0.f), wv[2 * j + 1], acc1);
    }

    // Reduce across the 8-lane group (xor masks stay within the group).
    acc0 += __shfl_xor(acc0, 1);
    acc1 += __shfl_xor(acc1, 1);
    acc0 += __shfl_xor(acc0, 2);
    acc1 += __shfl_xor(acc1, 2);
    acc0 += __shfl_xor(acc0, 4);
    acc1 += __shfl_xor(acc1, 4);

    if (c == 0) {
        float bb = b2[0];
        if (has1) {
            *(float2*)(out + e0) = make_float2(acc0 + bb, acc1 + bb);
        } else {
            out[e0] = acc0 + bb;
        }
    }
}

extern "C" void kernel_launch(void* const* d_in, const int* in_sizes, int n_in,
                              void* d_out, int out_size, void* d_ws, size_t ws_size,
                              hipStream_t stream) {
    const float* K_h = (const float*)d_in[0];
    const float* Q_h = (const float*)d_in[1];
    const float* P_e = (const float*)d_in[2];
    const int*   src = (const int*)d_in[3];
    const int*   dst = (const int*)d_in[4];
    const float* W1  = (const float*)d_in[5];
    const float* b1  = (const float*)d_in[6];
    const float* W2  = (const float*)d_in[7];
    const float* b2  = (const float*)d_in[8];
    float* out = (float*)d_out;

    int n_nodes = in_sizes[0] / DD;
    int n_edges = in_sizes[3];

    // Workspace: A [n][64] fp16, B [n][64] fp16 (12.8 MB total)
    __half* A  = (__half*)d_ws;
    __half* Bm = A + (size_t)n_nodes * DD;

    node_transform_kernel<<<(n_nodes + NPB - 1) / NPB, 256, 0, stream>>>(
        K_h, Q_h, P_e, W1, b1, A, Bm, n_nodes);
    // 64 edges per block (8 lanes per edge, 2 edges per lane-group)
    edge_score_kernel<<<(n_edges + 63) / 64, 256, 0, stream>>>(
        A, Bm, src, dst, W2, b2, out, n_edges);
}

// Round 5
// 132.502 us; speedup vs baseline: 1.0708x; 1.0708x over previous
//
#include <hip/hip_runtime.h>
#include <hip/hip_fp16.h>

#define DD 64
#define NPB 64          // nodes per block (node kernel)
#define LS 68           // padded LDS row stride (floats)

// Node-level transform, GEMM-tiled:
//   A = (K_h + P_e) @ W1 + b1   (stored fp16)
//   B = Q_h @ W1                (stored fp16)
__global__ __launch_bounds__(256) void node_transform_kernel(
    const float* __restrict__ K_h, const float* __restrict__ Q_h,
    const float* __restrict__ P_e, const float* __restrict__ W1,
    const float* __restrict__ b1, __half* __restrict__ A,
    __half* __restrict__ Bm, int n_nodes)
{
    __shared__ float kpT[DD][LS];  // [k][node_local]  (K+P, transposed)
    __shared__ float qT [DD][LS];  // [k][node_local]  (Q, transposed)
    __shared__ float ws [DD][DD];  // [k][c] — same layout as global W1

    const int tid   = threadIdx.x;
    const int nbase = blockIdx.x * NPB;

    // ---- Stage W1 straight copy (16 KB): coalesced float4 ----
    {
        const float4* w4 = (const float4*)W1;
        float4* s4 = (float4*)&ws[0][0];
#pragma unroll
        for (int j = 0; j < 4; ++j) {
            int idx = tid + j * 256;   // 1024 float4 total
            s4[idx] = w4[idx];
        }
    }

    // ---- Stage X transposed ----
#pragma unroll
    for (int j = 0; j < 4; ++j) {
        int chunk = tid + j * 256;        // float4 index over [64 nodes][16]
        int r  = chunk >> 4;              // node_local 0..63
        int k0 = (chunk & 15) << 2;       // 0,4,...,60
        int node = nbase + r;
        float4 kv = make_float4(0.f, 0.f, 0.f, 0.f);
        float4 pv = kv, qv = kv;
        if (node < n_nodes) {
            kv = *(const float4*)(K_h + (size_t)node * DD + k0);
            pv = *(const float4*)(P_e + (size_t)node * DD + k0);
            qv = *(const float4*)(Q_h + (size_t)node * DD + k0);
        }
        kpT[k0 + 0][r] = kv.x + pv.x;
        kpT[k0 + 1][r] = kv.y + pv.y;
        kpT[k0 + 2][r] = kv.z + pv.z;
        kpT[k0 + 3][r] = kv.w + pv.w;
        qT [k0 + 0][r] = qv.x;
        qT [k0 + 1][r] = qv.y;
        qT [k0 + 2][r] = qv.z;
        qT [k0 + 3][r] = qv.w;
    }
    __syncthreads();

    // ---- Main loop: 4x4 micro-tile, dual accumulators (A and B) ----
    const int tx = tid & 15;
    const int ty = tid >> 4;
    const int c0 = tx * 4;
    const int r0 = ty * 4;

    float4 bv = *(const float4*)(b1 + c0);   // fold b1 into A accumulator
    float accA[4][4], accB[4][4];
#pragma unroll
    for (int r = 0; r < 4; ++r) {
        accA[r][0] = bv.x; accA[r][1] = bv.y; accA[r][2] = bv.z; accA[r][3] = bv.w;
        accB[r][0] = 0.f;  accB[r][1] = 0.f;  accB[r][2] = 0.f;  accB[r][3] = 0.f;
    }

#pragma unroll 8
    for (int k = 0; k < DD; ++k) {
        float4 a4 = *(const float4*)&kpT[k][r0];
        float4 q4 = *(const float4*)&qT [k][r0];
        float4 w4 = *(const float4*)&ws [k][c0];
        const float av[4] = {a4.x, a4.y, a4.z, a4.w};
        const float qv[4] = {q4.x, q4.y, q4.z, q4.w};
        const float wv[4] = {w4.x, w4.y, w4.z, w4.w};
#pragma unroll
        for (int r = 0; r < 4; ++r) {
#pragma unroll
            for (int c = 0; c < 4; ++c) {
                accA[r][c] = fmaf(av[r], wv[c], accA[r][c]);
                accB[r][c] = fmaf(qv[r], wv[c], accB[r][c]);
            }
        }
    }

    // ---- Epilogue: convert to fp16, 8 B stores ----
#pragma unroll
    for (int r = 0; r < 4; ++r) {
        int node = nbase + r0 + r;
        if (node >= n_nodes) continue;
        union { __half2 h[2]; float2 f; } ua, ub;
        ua.h[0] = __float22half2_rn(make_float2(accA[r][0], accA[r][1]));
        ua.h[1] = __float22half2_rn(make_float2(accA[r][2], accA[r][3]));
        ub.h[0] = __float22half2_rn(make_float2(accB[r][0], accB[r][1]));
        ub.h[1] = __float22half2_rn(make_float2(accB[r][2], accB[r][3]));
        *(float2*)(A  + (size_t)node * DD + c0) = ua.f;
        *(float2*)(Bm + (size_t)node * DD + c0) = ub.f;
    }
}

// Edge-level: score[e] = relu(A[src[e]] - B[dst[e]]) . W2 + b2
// 8 lanes cooperate per edge, 2 edges per lane-group.
// PLAIN loads (no nontemporal): each A/B row is reused ~16x across edges
// (800k edges / 50k nodes) — L2/L3 retention of the 12.8 MB working set is
// where that reuse is harvested. R4's nt-demotion cost ~8 us.
__global__ __launch_bounds__(256) void edge_score_kernel(
    const __half* __restrict__ A, const __half* __restrict__ Bm,
    const int* __restrict__ src, const int* __restrict__ dst,
    const float* __restrict__ W2, const float* __restrict__ b2,
    float* __restrict__ out, int n_edges)
{
    const int tid = threadIdx.x;
    const int g   = tid >> 3;                 // lane-group 0..31
    const int c   = tid & 7;                  // 16B chunk within row
    const int e0  = (blockIdx.x << 6) + (g << 1);   // 64 edges per block
    const int e1  = e0 + 1;
    if (e0 >= n_edges) return;

    const int s0 = src[e0], d0 = dst[e0];
    const bool has1 = (e1 < n_edges);
    const int s1 = has1 ? src[e1] : s0;
    const int d1 = has1 ? dst[e1] : d0;

    // Issue all 4 row loads back-to-back (32 outstanding lines per wave).
    float4 a0  = *(const float4*)(A  + (size_t)s0 * DD + c * 8);
    float4 b0  = *(const float4*)(Bm + (size_t)d0 * DD + c * 8);
    float4 a1  = *(const float4*)(A  + (size_t)s1 * DD + c * 8);
    float4 b1v = *(const float4*)(Bm + (size_t)d1 * DD + c * 8);

    float4 w0 = *(const float4*)(W2 + c * 8);       // uniform -> s_load
    float4 w1 = *(const float4*)(W2 + c * 8 + 4);
    const float wv[8] = {w0.x, w0.y, w0.z, w0.w, w1.x, w1.y, w1.z, w1.w};

    const __half2* ah0 = (const __half2*)&a0;
    const __half2* bh0 = (const __half2*)&b0;
    const __half2* ah1 = (const __half2*)&a1;
    const __half2* bh1 = (const __half2*)&b1v;

    float acc0 = 0.f, acc1 = 0.f;
#pragma unroll
    for (int j = 0; j < 4; ++j) {
        float2 x0 = __half22float2(ah0[j]);
        float2 y0 = __half22float2(bh0[j]);
        float2 x1 = __half22float2(ah1[j]);
        float2 y1 = __half22float2(bh1[j]);
        acc0 = fmaf(fmaxf(x0.x - y0.x, 0.f), wv[2 * j + 0], acc0);
        acc0 = fmaf(fmaxf(x0.y - y0.y, 0.f), wv[2 * j + 1], acc0);
        acc1 = fmaf(fmaxf(x1.x - y1.x, 0.f), wv[2 * j + 0], acc1);
        acc1 = fmaf(fmaxf(x1.y - y1.y, 0.f), wv[2 * j + 1], acc1);
    }

    // Reduce across the 8-lane group (xor masks stay within the group).
    acc0 += __shfl_xor(acc0, 1);
    acc1 += __shfl_xor(acc1, 1);
    acc0 += __shfl_xor(acc0, 2);
    acc1 += __shfl_xor(acc1, 2);
    acc0 += __shfl_xor(acc0, 4);
    acc1 += __shfl_xor(acc1, 4);

    if (c == 0) {
        float bb = b2[0];
        if (has1) {
            *(float2*)(out + e0) = make_float2(acc0 + bb, acc1 + bb);
        } else {
            out[e0] = acc0 + bb;
        }
    }
}

extern "C" void kernel_launch(void* const* d_in, const int* in_sizes, int n_in,
                              void* d_out, int out_size, void* d_ws, size_t ws_size,
                              hipStream_t stream) {
    const float* K_h = (const float*)d_in[0];
    const float* Q_h = (const float*)d_in[1];
    const float* P_e = (const float*)d_in[2];
    const int*   src = (const int*)d_in[3];
    const int*   dst = (const int*)d_in[4];
    const float* W1  = (const float*)d_in[5];
    const float* b1  = (const float*)d_in[6];
    const float* W2  = (const float*)d_in[7];
    const float* b2  = (const float*)d_in[8];
    float* out = (float*)d_out;

    int n_nodes = in_sizes[0] / DD;
    int n_edges = in_sizes[3];

    // Workspace: A [n][64] fp16, B [n][64] fp16 (12.8 MB total)
    __half* A  = (__half*)d_ws;
    __half* Bm = A + (size_t)n_nodes * DD;

    node_transform_kernel<<<(n_nodes + NPB - 1) / NPB, 256, 0, stream>>>(
        K_h, Q_h, P_e, W1, b1, A, Bm, n_nodes);
    // 64 edges per block (8 lanes per edge, 2 edges per lane-group)
    edge_score_kernel<<<(n_edges + 63) / 64, 256, 0, stream>>>(
        A, Bm, src, dst, W2, b2, out, n_edges);
}

// Round 6
// 131.268 us; speedup vs baseline: 1.0808x; 1.0094x over previous
//
#include <hip/hip_runtime.h>
#include <hip/hip_fp16.h>

#define DD 64
#define NPB 64          // nodes per block (node kernel)
#define LS 68           // padded LDS row stride (floats)

// Node-level transform, GEMM-tiled:
//   A = (K_h + P_e) @ W1 + b1   (stored fp16)
//   B = Q_h @ W1                (stored fp16)
__global__ __launch_bounds__(256) void node_transform_kernel(
    const float* __restrict__ K_h, const float* __restrict__ Q_h,
    const float* __restrict__ P_e, const float* __restrict__ W1,
    const float* __restrict__ b1, __half* __restrict__ A,
    __half* __restrict__ Bm, int n_nodes)
{
    __shared__ float kpT[DD][LS];  // [k][node_local]  (K+P, transposed)
    __shared__ float qT [DD][LS];  // [k][node_local]  (Q, transposed)
    __shared__ float ws [DD][DD];  // [k][c] — same layout as global W1

    const int tid   = threadIdx.x;
    const int nbase = blockIdx.x * NPB;

    // ---- Stage W1 straight copy (16 KB): coalesced float4 ----
    {
        const float4* w4 = (const float4*)W1;
        float4* s4 = (float4*)&ws[0][0];
#pragma unroll
        for (int j = 0; j < 4; ++j) {
            int idx = tid + j * 256;   // 1024 float4 total
            s4[idx] = w4[idx];
        }
    }

    // ---- Stage X transposed ----
#pragma unroll
    for (int j = 0; j < 4; ++j) {
        int chunk = tid + j * 256;        // float4 index over [64 nodes][16]
        int r  = chunk >> 4;              // node_local 0..63
        int k0 = (chunk & 15) << 2;       // 0,4,...,60
        int node = nbase + r;
        float4 kv = make_float4(0.f, 0.f, 0.f, 0.f);
        float4 pv = kv, qv = kv;
        if (node < n_nodes) {
            kv = *(const float4*)(K_h + (size_t)node * DD + k0);
            pv = *(const float4*)(P_e + (size_t)node * DD + k0);
            qv = *(const float4*)(Q_h + (size_t)node * DD + k0);
        }
        kpT[k0 + 0][r] = kv.x + pv.x;
        kpT[k0 + 1][r] = kv.y + pv.y;
        kpT[k0 + 2][r] = kv.z + pv.z;
        kpT[k0 + 3][r] = kv.w + pv.w;
        qT [k0 + 0][r] = qv.x;
        qT [k0 + 1][r] = qv.y;
        qT [k0 + 2][r] = qv.z;
        qT [k0 + 3][r] = qv.w;
    }
    __syncthreads();

    // ---- Main loop: 4x4 micro-tile, dual accumulators (A and B) ----
    const int tx = tid & 15;
    const int ty = tid >> 4;
    const int c0 = tx * 4;
    const int r0 = ty * 4;

    float4 bv = *(const float4*)(b1 + c0);   // fold b1 into A accumulator
    float accA[4][4], accB[4][4];
#pragma unroll
    for (int r = 0; r < 4; ++r) {
        accA[r][0] = bv.x; accA[r][1] = bv.y; accA[r][2] = bv.z; accA[r][3] = bv.w;
        accB[r][0] = 0.f;  accB[r][1] = 0.f;  accB[r][2] = 0.f;  accB[r][3] = 0.f;
    }

#pragma unroll 8
    for (int k = 0; k < DD; ++k) {
        float4 a4 = *(const float4*)&kpT[k][r0];
        float4 q4 = *(const float4*)&qT [k][r0];
        float4 w4 = *(const float4*)&ws [k][c0];
        const float av[4] = {a4.x, a4.y, a4.z, a4.w};
        const float qv[4] = {q4.x, q4.y, q4.z, q4.w};
        const float wv[4] = {w4.x, w4.y, w4.z, w4.w};
#pragma unroll
        for (int r = 0; r < 4; ++r) {
#pragma unroll
            for (int c = 0; c < 4; ++c) {
                accA[r][c] = fmaf(av[r], wv[c], accA[r][c]);
                accB[r][c] = fmaf(qv[r], wv[c], accB[r][c]);
            }
        }
    }

    // ---- Epilogue: convert to fp16, 8 B stores ----
#pragma unroll
    for (int r = 0; r < 4; ++r) {
        int node = nbase + r0 + r;
        if (node >= n_nodes) continue;
        union { __half2 h[2]; float2 f; } ua, ub;
        ua.h[0] = __float22half2_rn(make_float2(accA[r][0], accA[r][1]));
        ua.h[1] = __float22half2_rn(make_float2(accA[r][2], accA[r][3]));
        ub.h[0] = __float22half2_rn(make_float2(accB[r][0], accB[r][1]));
        ub.h[1] = __float22half2_rn(make_float2(accB[r][2], accB[r][3]));
        *(float2*)(A  + (size_t)node * DD + c0) = ua.f;
        *(float2*)(Bm + (size_t)node * DD + c0) = ub.f;
    }
}

// Edge-level: score[e] = relu(A[src[e]] - B[dst[e]]) . W2 + b2
// 8 lanes per edge, 4 edges per lane-group:
//  - 2x int4 index loads (broadcast-coalesced) replace 4 scalar index loads
//  - 8 row-gathers issued back-to-back -> 64 lines in flight per wave,
//    amortizing the index->gather dependent-latency chain over 4 edges
//  - lane 0 writes the 4 scores as one aligned float4
// PLAIN loads (no nt): rows are reused ~16x; L2/L3 retention is the win.
__global__ __launch_bounds__(256) void edge_score_kernel(
    const __half* __restrict__ A, const __half* __restrict__ Bm,
    const int* __restrict__ src, const int* __restrict__ dst,
    const float* __restrict__ W2, const float* __restrict__ b2,
    float* __restrict__ out, int n_edges)
{
    const int tid = threadIdx.x;
    const int g   = tid >> 3;                   // lane-group 0..31
    const int c   = tid & 7;                    // 16B chunk within row
    const int e0  = (blockIdx.x << 7) + (g << 2);  // 128 edges per block
    if (e0 >= n_edges) return;

    float4 w0 = *(const float4*)(W2 + c * 8);   // uniform -> s_load
    float4 w1 = *(const float4*)(W2 + c * 8 + 4);
    const float wv[8] = {w0.x, w0.y, w0.z, w0.w, w1.x, w1.y, w1.z, w1.w};
    const size_t coff = (size_t)(c * 8);

    if (e0 + 3 < n_edges) {
        int4 sv = *(const int4*)(src + e0);     // e0 % 4 == 0 -> aligned
        int4 dv = *(const int4*)(dst + e0);

        // Issue all 8 row loads back-to-back.
        float4 ra0 = *(const float4*)(A  + (size_t)sv.x * DD + coff);
        float4 rb0 = *(const float4*)(Bm + (size_t)dv.x * DD + coff);
        float4 ra1 = *(const float4*)(A  + (size_t)sv.y * DD + coff);
        float4 rb1 = *(const float4*)(Bm + (size_t)dv.y * DD + coff);
        float4 ra2 = *(const float4*)(A  + (size_t)sv.z * DD + coff);
        float4 rb2 = *(const float4*)(Bm + (size_t)dv.z * DD + coff);
        float4 ra3 = *(const float4*)(A  + (size_t)sv.w * DD + coff);
        float4 rb3 = *(const float4*)(Bm + (size_t)dv.w * DD + coff);

        float acc0 = 0.f, acc1 = 0.f, acc2 = 0.f, acc3 = 0.f;
        const __half2* ah0 = (const __half2*)&ra0;
        const __half2* bh0 = (const __half2*)&rb0;
        const __half2* ah1 = (const __half2*)&ra1;
        const __half2* bh1 = (const __half2*)&rb1;
        const __half2* ah2 = (const __half2*)&ra2;
        const __half2* bh2 = (const __half2*)&rb2;
        const __half2* ah3 = (const __half2*)&ra3;
        const __half2* bh3 = (const __half2*)&rb3;
#pragma unroll
        for (int j = 0; j < 4; ++j) {
            float2 x, y;
            x = __half22float2(ah0[j]); y = __half22float2(bh0[j]);
            acc0 = fmaf(fmaxf(x.x - y.x, 0.f), wv[2 * j + 0], acc0);
            acc0 = fmaf(fmaxf(x.y - y.y, 0.f), wv[2 * j + 1], acc0);
            x = __half22float2(ah1[j]); y = __half22float2(bh1[j]);
            acc1 = fmaf(fmaxf(x.x - y.x, 0.f), wv[2 * j + 0], acc1);
            acc1 = fmaf(fmaxf(x.y - y.y, 0.f), wv[2 * j + 1], acc1);
            x = __half22float2(ah2[j]); y = __half22float2(bh2[j]);
            acc2 = fmaf(fmaxf(x.x - y.x, 0.f), wv[2 * j + 0], acc2);
            acc2 = fmaf(fmaxf(x.y - y.y, 0.f), wv[2 * j + 1], acc2);
            x = __half22float2(ah3[j]); y = __half22float2(bh3[j]);
            acc3 = fmaf(fmaxf(x.x - y.x, 0.f), wv[2 * j + 0], acc3);
            acc3 = fmaf(fmaxf(x.y - y.y, 0.f), wv[2 * j + 1], acc3);
        }

        // Reduce across the 8-lane group (xor masks stay within the group).
        acc0 += __shfl_xor(acc0, 1); acc1 += __shfl_xor(acc1, 1);
        acc2 += __shfl_xor(acc2, 1); acc3 += __shfl_xor(acc3, 1);
        acc0 += __shfl_xor(acc0, 2); acc1 += __shfl_xor(acc1, 2);
        acc2 += __shfl_xor(acc2, 2); acc3 += __shfl_xor(acc3, 2);
        acc0 += __shfl_xor(acc0, 4); acc1 += __shfl_xor(acc1, 4);
        acc2 += __shfl_xor(acc2, 4); acc3 += __shfl_xor(acc3, 4);

        if (c == 0) {
            float bb = b2[0];
            *(float4*)(out + e0) =
                make_float4(acc0 + bb, acc1 + bb, acc2 + bb, acc3 + bb);
        }
    } else {
        // Tail: per-edge scalar path (same math).
        for (int e = e0; e < n_edges && e < e0 + 4; ++e) {
            int s = src[e], d = dst[e];
            float4 ar = *(const float4*)(A  + (size_t)s * DD + coff);
            float4 br = *(const float4*)(Bm + (size_t)d * DD + coff);
            const __half2* ah = (const __half2*)&ar;
            const __half2* bh = (const __half2*)&br;
            float acc = 0.f;
#pragma unroll
            for (int j = 0; j < 4; ++j) {
                float2 x = __half22float2(ah[j]);
                float2 y = __half22float2(bh[j]);
                acc = fmaf(fmaxf(x.x - y.x, 0.f), wv[2 * j + 0], acc);
                acc = fmaf(fmaxf(x.y - y.y, 0.f), wv[2 * j + 1], acc);
            }
            acc += __shfl_xor(acc, 1);
            acc += __shfl_xor(acc, 2);
            acc += __shfl_xor(acc, 4);
            if (c == 0) out[e] = acc + b2[0];
        }
    }
}

extern "C" void kernel_launch(void* const* d_in, const int* in_sizes, int n_in,
                              void* d_out, int out_size, void* d_ws, size_t ws_size,
                              hipStream_t stream) {
    const float* K_h = (const float*)d_in[0];
    const float* Q_h = (const float*)d_in[1];
    const float* P_e = (const float*)d_in[2];
    const int*   src = (const int*)d_in[3];
    const int*   dst = (const int*)d_in[4];
    const float* W1  = (const float*)d_in[5];
    const float* b1  = (const float*)d_in[6];
    const float* W2  = (const float*)d_in[7];
    const float* b2  = (const float*)d_in[8];
    float* out = (float*)d_out;

    int n_nodes = in_sizes[0] / DD;
    int n_edges = in_sizes[3];

    // Workspace: A [n][64] fp16, B [n][64] fp16 (12.8 MB total)
    __half* A  = (__half*)d_ws;
    __half* Bm = A + (size_t)n_nodes * DD;

    node_transform_kernel<<<(n_nodes + NPB - 1) / NPB, 256, 0, stream>>>(
        K_h, Q_h, P_e, W1, b1, A, Bm, n_nodes);
    // 128 edges per block (8 lanes per edge, 4 edges per lane-group)
    edge_score_kernel<<<(n_edges + 127) / 128, 256, 0, stream>>>(
        A, Bm, src, dst, W2, b2, out, n_edges);
}

// Round 7
// 121.315 us; speedup vs baseline: 1.1695x; 1.0820x over previous
//
#include <hip/hip_runtime.h>
#include <hip/hip_fp16.h>

#define DD 64
#define NPB 64          // nodes per block (node kernel)
#define LP 72           // padded LDS row stride in halves (144 B): 2-way-only bank aliasing

typedef _Float16 f16x8 __attribute__((ext_vector_type(8)));
typedef float    f32x4 __attribute__((ext_vector_type(4)));

// Node-level transform on MFMA f16 (fp32 accumulate):
//   A = (K_h + P_e) @ W1 + b1   (stored fp16)
//   B = Q_h @ W1                (stored fp16)
// 64 nodes/block, 4 waves; wave w computes rows w*16..w*16+15 of BOTH outputs
// via 16x16x32 MFMA (2 k-halves x 4 col-tiles x {A,B} = 16 mfma/wave).
// A-operand: lane holds X[m=lane&15][k=quad*8+j]; B-operand: W1T[n=lane&15][k]
// contiguous; C/D: col=lane&15, row=quad*4+reg (m89/m91-verified mapping).
__global__ __launch_bounds__(256) void node_transform_mfma(
    const float* __restrict__ K_h, const float* __restrict__ Q_h,
    const float* __restrict__ P_e, const float* __restrict__ W1,
    const float* __restrict__ b1, __half* __restrict__ A,
    __half* __restrict__ Bm, int n_nodes)
{
    __shared__ __half XH [NPB][LP];   // fp16(K+P)
    __shared__ __half QH [NPB][LP];   // fp16(Q)
    __shared__ __half W1T[DD][LP];    // W1 transposed: W1T[n][k] = W1[k][n]

    const int tid   = threadIdx.x;
    const int nbase = blockIdx.x * NPB;

    // ---- Stage W1T (8 KB): thread t reads W1[k][n0..n0+15], scatters column-wise ----
    {
        const int k  = tid >> 2;
        const int n0 = (tid & 3) << 4;
        const float* wr = W1 + k * DD + n0;
        float4 w0 = *(const float4*)(wr);
        float4 w1v = *(const float4*)(wr + 4);
        float4 w2v = *(const float4*)(wr + 8);
        float4 w3v = *(const float4*)(wr + 12);
        const float wv[16] = {w0.x,w0.y,w0.z,w0.w, w1v.x,w1v.y,w1v.z,w1v.w,
                              w2v.x,w2v.y,w2v.z,w2v.w, w3v.x,w3v.y,w3v.z,w3v.w};
#pragma unroll
        for (int j = 0; j < 16; ++j)
            W1T[n0 + j][k] = __float2half(wv[j]);
    }

    // ---- Stage XH = fp16(K+P), QH = fp16(Q); coalesced float4 global reads ----
#pragma unroll
    for (int ch = 0; ch < 4; ++ch) {
        int idx = tid + (ch << 8);        // float4 index over [64 rows][16]
        int r   = idx >> 4;
        int q4  = idx & 15;
        int node = nbase + r;
        float4 kv = make_float4(0.f,0.f,0.f,0.f);
        float4 pv = kv, qv = kv;
        if (node < n_nodes) {
            kv = *(const float4*)(K_h + (size_t)node * DD + q4 * 4);
            pv = *(const float4*)(P_e + (size_t)node * DD + q4 * 4);
            qv = *(const float4*)(Q_h + (size_t)node * DD + q4 * 4);
        }
        __half2* xh = (__half2*)&XH[r][q4 << 2];
        xh[0] = __float22half2_rn(make_float2(kv.x + pv.x, kv.y + pv.y));
        xh[1] = __float22half2_rn(make_float2(kv.z + pv.z, kv.w + pv.w));
        __half2* qh = (__half2*)&QH[r][q4 << 2];
        qh[0] = __float22half2_rn(make_float2(qv.x, qv.y));
        qh[1] = __float22half2_rn(make_float2(qv.z, qv.w));
    }
    __syncthreads();

    // ---- MFMA main: wave w, lane (m = lane&15, q = lane>>4) ----
    const int w    = tid >> 6;
    const int lane = tid & 63;
    const int m    = lane & 15;
    const int q    = lane >> 4;
    const int row  = (w << 4) + m;

    f16x8 xlo = *(const f16x8*)&XH[row][(q << 3)];
    f16x8 xhi = *(const f16x8*)&XH[row][32 + (q << 3)];
    f16x8 qlo = *(const f16x8*)&QH[row][(q << 3)];
    f16x8 qhi = *(const f16x8*)&QH[row][32 + (q << 3)];

    f32x4 accA[4], accB[4];
#pragma unroll
    for (int t = 0; t < 4; ++t) {
        float bb = b1[t * 16 + m];            // b1 folded into A accumulator
        accA[t] = (f32x4){bb, bb, bb, bb};
        accB[t] = (f32x4){0.f, 0.f, 0.f, 0.f};
        f16x8 wlo = *(const f16x8*)&W1T[t * 16 + m][(q << 3)];
        f16x8 whi = *(const f16x8*)&W1T[t * 16 + m][32 + (q << 3)];
        accA[t] = __builtin_amdgcn_mfma_f32_16x16x32_f16(xlo, wlo, accA[t], 0, 0, 0);
        accA[t] = __builtin_amdgcn_mfma_f32_16x16x32_f16(xhi, whi, accA[t], 0, 0, 0);
        accB[t] = __builtin_amdgcn_mfma_f32_16x16x32_f16(qlo, wlo, accB[t], 0, 0, 0);
        accB[t] = __builtin_amdgcn_mfma_f32_16x16x32_f16(qhi, whi, accB[t], 0, 0, 0);
    }

    // ---- Store: acc[t][r] -> out[nbase + w*16 + q*4 + r][t*16 + m] ----
#pragma unroll
    for (int r = 0; r < 4; ++r) {
        int node = nbase + (w << 4) + (q << 2) + r;
        if (node >= n_nodes) continue;
        __half* Arow = A  + (size_t)node * DD + m;
        __half* Brow = Bm + (size_t)node * DD + m;
#pragma unroll
        for (int t = 0; t < 4; ++t) {
            Arow[t * 16] = __float2half(accA[t][r]);
            Brow[t * 16] = __float2half(accB[t][r]);
        }
    }
}

// Edge-level: score[e] = relu(A[src[e]] - B[dst[e]]) . W2 + b2
// 8 lanes per edge, 4 edges per lane-group (R6 — at the L2-miss request wall).
__global__ __launch_bounds__(256) void edge_score_kernel(
    const __half* __restrict__ A, const __half* __restrict__ Bm,
    const int* __restrict__ src, const int* __restrict__ dst,
    const float* __restrict__ W2, const float* __restrict__ b2,
    float* __restrict__ out, int n_edges)
{
    const int tid = threadIdx.x;
    const int g   = tid >> 3;                   // lane-group 0..31
    const int c   = tid & 7;                    // 16B chunk within row
    const int e0  = (blockIdx.x << 7) + (g << 2);  // 128 edges per block
    if (e0 >= n_edges) return;

    float4 w0 = *(const float4*)(W2 + c * 8);   // uniform -> s_load
    float4 w1 = *(const float4*)(W2 + c * 8 + 4);
    const float wv[8] = {w0.x, w0.y, w0.z, w0.w, w1.x, w1.y, w1.z, w1.w};
    const size_t coff = (size_t)(c * 8);

    if (e0 + 3 < n_edges) {
        int4 sv = *(const int4*)(src + e0);     // e0 % 4 == 0 -> aligned
        int4 dv = *(const int4*)(dst + e0);

        // Issue all 8 row loads back-to-back.
        float4 ra0 = *(const float4*)(A  + (size_t)sv.x * DD + coff);
        float4 rb0 = *(const float4*)(Bm + (size_t)dv.x * DD + coff);
        float4 ra1 = *(const float4*)(A  + (size_t)sv.y * DD + coff);
        float4 rb1 = *(const float4*)(Bm + (size_t)dv.y * DD + coff);
        float4 ra2 = *(const float4*)(A  + (size_t)sv.z * DD + coff);
        float4 rb2 = *(const float4*)(Bm + (size_t)dv.z * DD + coff);
        float4 ra3 = *(const float4*)(A  + (size_t)sv.w * DD + coff);
        float4 rb3 = *(const float4*)(Bm + (size_t)dv.w * DD + coff);

        float acc0 = 0.f, acc1 = 0.f, acc2 = 0.f, acc3 = 0.f;
        const __half2* ah0 = (const __half2*)&ra0;
        const __half2* bh0 = (const __half2*)&rb0;
        const __half2* ah1 = (const __half2*)&ra1;
        const __half2* bh1 = (const __half2*)&rb1;
        const __half2* ah2 = (const __half2*)&ra2;
        const __half2* bh2 = (const __half2*)&rb2;
        const __half2* ah3 = (const __half2*)&ra3;
        const __half2* bh3 = (const __half2*)&rb3;
#pragma unroll
        for (int j = 0; j < 4; ++j) {
            float2 x, y;
            x = __half22float2(ah0[j]); y = __half22float2(bh0[j]);
            acc0 = fmaf(fmaxf(x.x - y.x, 0.f), wv[2 * j + 0], acc0);
            acc0 = fmaf(fmaxf(x.y - y.y, 0.f), wv[2 * j + 1], acc0);
            x = __half22float2(ah1[j]); y = __half22float2(bh1[j]);
            acc1 = fmaf(fmaxf(x.x - y.x, 0.f), wv[2 * j + 0], acc1);
            acc1 = fmaf(fmaxf(x.y - y.y, 0.f), wv[2 * j + 1], acc1);
            x = __half22float2(ah2[j]); y = __half22float2(bh2[j]);
            acc2 = fmaf(fmaxf(x.x - y.x, 0.f), wv[2 * j + 0], acc2);
            acc2 = fmaf(fmaxf(x.y - y.y, 0.f), wv[2 * j + 1], acc2);
            x = __half22float2(ah3[j]); y = __half22float2(bh3[j]);
            acc3 = fmaf(fmaxf(x.x - y.x, 0.f), wv[2 * j + 0], acc3);
            acc3 = fmaf(fmaxf(x.y - y.y, 0.f), wv[2 * j + 1], acc3);
        }

        acc0 += __shfl_xor(acc0, 1); acc1 += __shfl_xor(acc1, 1);
        acc2 += __shfl_xor(acc2, 1); acc3 += __shfl_xor(acc3, 1);
        acc0 += __shfl_xor(acc0, 2); acc1 += __shfl_xor(acc1, 2);
        acc2 += __shfl_xor(acc2, 2); acc3 += __shfl_xor(acc3, 2);
        acc0 += __shfl_xor(acc0, 4); acc1 += __shfl_xor(acc1, 4);
        acc2 += __shfl_xor(acc2, 4); acc3 += __shfl_xor(acc3, 4);

        if (c == 0) {
            float bb = b2[0];
            *(float4*)(out + e0) =
                make_float4(acc0 + bb, acc1 + bb, acc2 + bb, acc3 + bb);
        }
    } else {
        for (int e = e0; e < n_edges && e < e0 + 4; ++e) {
            int s = src[e], d = dst[e];
            float4 ar = *(const float4*)(A  + (size_t)s * DD + coff);
            float4 br = *(const float4*)(Bm + (size_t)d * DD + coff);
            const __half2* ah = (const __half2*)&ar;
            const __half2* bh = (const __half2*)&br;
            float acc = 0.f;
#pragma unroll
            for (int j = 0; j < 4; ++j) {
                float2 x = __half22float2(ah[j]);
                float2 y = __half22float2(bh[j]);
                acc = fmaf(fmaxf(x.x - y.x, 0.f), wv[2 * j + 0], acc);
                acc = fmaf(fmaxf(x.y - y.y, 0.f), wv[2 * j + 1], acc);
            }
            acc += __shfl_xor(acc, 1);
            acc += __shfl_xor(acc, 2);
            acc += __shfl_xor(acc, 4);
            if (c == 0) out[e] = acc + b2[0];
        }
    }
}

extern "C" void kernel_launch(void* const* d_in, const int* in_sizes, int n_in,
                              void* d_out, int out_size, void* d_ws, size_t ws_size,
                              hipStream_t stream) {
    const float* K_h = (const float*)d_in[0];
    const float* Q_h = (const float*)d_in[1];
    const float* P_e = (const float*)d_in[2];
    const int*   src = (const int*)d_in[3];
    const int*   dst = (const int*)d_in[4];
    const float* W1  = (const float*)d_in[5];
    const float* b1  = (const float*)d_in[6];
    const float* W2  = (const float*)d_in[7];
    const float* b2  = (const float*)d_in[8];
    float* out = (float*)d_out;

    int n_nodes = in_sizes[0] / DD;
    int n_edges = in_sizes[3];

    // Workspace: A [n][64] fp16, B [n][64] fp16 (12.8 MB total)
    __half* A  = (__half*)d_ws;
    __half* Bm = A + (size_t)n_nodes * DD;

    node_transform_mfma<<<(n_nodes + NPB - 1) / NPB, 256, 0, stream>>>(
        K_h, Q_h, P_e, W1, b1, A, Bm, n_nodes);
    // 128 edges per block (8 lanes per edge, 4 edges per lane-group)
    edge_score_kernel<<<(n_edges + 127) / 128, 256, 0, stream>>>(
        A, Bm, src, dst, W2, b2, out, n_edges);
}